// Round 2
// baseline (69.852 us; speedup 1.0000x reference)
//
#include <hip/hip_runtime.h>

// Problem constants (from reference)
constexpr int Bn    = 262144;
constexpr int NNUM  = 64;
constexpr int FCAT  = 32;
constexpr int NCAT  = 8;
constexpr int NFEAT = NNUM + FCAT * NCAT;  // 320
constexpr int NPHEN = NNUM + FCAT;         // 96

// tanh(x) given a = 2x:  tanh(x) = 1 - 2/(exp(2x)+1)
__device__ __forceinline__ float tanh_from_2x(float a) {
    float e = __expf(a);
    float r = __builtin_amdgcn_rcpf(e + 1.0f);
    return fmaf(-2.0f, r, 1.0f);
}

// Async global->LDS, 16B per lane. LDS dest = wave-uniform base + lane*16.
__device__ __forceinline__ void gload_lds16(const void* g, void* l) {
    __builtin_amdgcn_global_load_lds(
        (const __attribute__((address_space(1))) void*)g,
        (__attribute__((address_space(3))) void*)l,
        16, 0, 0);
}

__global__ __launch_bounds__(256) void model_kernel(
    const float* __restrict__ num_x,   // (B, 64)
    const float* __restrict__ cat_x,   // (32, B, 8)
    const float* __restrict__ W,       // (2, 320)
    const float* __restrict__ M,       // (2, 96)
    float* __restrict__ out)           // (2, B)
{
    // 256 rows x 16 float4, XOR-swizzled in the float4-column:
    // LDS slot s holds global float4 g(s) = (s>>4)*16 + ((s&15) ^ ((s>>4)&15)).
    __shared__ float4 sNum[256 * 16];          // 64 KB
    __shared__ float  sW2[2 * NFEAT];          // 2*W (exp arg ready)
    __shared__ float  sM[2 * NPHEN];

    const int tid  = threadIdx.x;
    const int lane = tid & 63;
    const int wave = tid >> 6;
    const int b0   = blockIdx.x * 256;
    const int b    = b0 + tid;

    // ---- async stage of this block's 64 KB num panel (fully coalesced;
    //      source address pre-swizzled so LDS stays linear per rule #21) ----
    {
        const float4* gnum = reinterpret_cast<const float4*>(num_x) + (size_t)b0 * 16;
        #pragma unroll
        for (int k = 0; k < 16; ++k) {
            const int sbase = wave * 1024 + k * 64;   // wave-uniform LDS base (slots)
            const int s = sbase + lane;
            const int r = s >> 4;
            const int g = r * 16 + ((s & 15) ^ (r & 15));
            gload_lds16(gnum + g, &sNum[sbase]);
        }
    }

    for (int i = tid; i < 2 * NFEAT; i += 256) sW2[i] = 2.0f * W[i];
    for (int i = tid; i < 2 * NPHEN; i += 256) sM[i]  = M[i];
    __syncthreads();   // compiler drains vmcnt(0) here -> sNum ready

    float f0 = 0.0f, f1 = 0.0f;

    // ---- numerical features from LDS (swizzled read-back) ----
    const int sw = tid & 15;
    #pragma unroll
    for (int j = 0; j < 16; ++j) {
        float4 v = sNum[tid * 16 + (j ^ sw)];   // = global float4 (row tid, col j)
        const float* vp = reinterpret_cast<const float*>(&v);
        #pragma unroll
        for (int jj = 0; jj < 4; ++jj) {
            const int k = j * 4 + jj;
            float x  = vp[jj];
            float t0 = tanh_from_2x(sW2[k] * x);
            float t1 = tanh_from_2x(sW2[NFEAT + k] * x);
            f0 = fmaf(sM[k], t0, f0);
            f1 = fmaf(sM[NPHEN + k], t1, f1);
        }
    }

    // ---- categorical features: fully coalesced per-lane float4 pairs ----
    #pragma unroll 4
    for (int f = 0; f < FCAT; ++f) {
        const float4* cx = reinterpret_cast<const float4*>(
            cat_x + (size_t)f * (size_t)Bn * NCAT + (size_t)b * NCAT);
        float4 v0 = cx[0];
        float4 v1 = cx[1];
        const float* vp0 = reinterpret_cast<const float*>(&v0);
        const float* vp1 = reinterpret_cast<const float*>(&v1);
        const float* w0 = &sW2[NNUM + f * NCAT];
        const float* w1 = &sW2[NFEAT + NNUM + f * NCAT];
        float d0 = 0.0f, d1 = 0.0f;            // accumulates 2*dot
        #pragma unroll
        for (int n = 0; n < 4; ++n) {
            d0 = fmaf(w0[n], vp0[n], d0);
            d1 = fmaf(w1[n], vp0[n], d1);
        }
        #pragma unroll
        for (int n = 0; n < 4; ++n) {
            d0 = fmaf(w0[4 + n], vp1[n], d0);
            d1 = fmaf(w1[4 + n], vp1[n], d1);
        }
        float t0 = tanh_from_2x(d0);
        float t1 = tanh_from_2x(d1);
        f0 = fmaf(sM[NNUM + f], t0, f0);
        f1 = fmaf(sM[NPHEN + NNUM + f], t1, f1);
    }

    // ---- stable 2-class softmax ----
    float e10 = __expf(f1 - f0);
    float o0  = __builtin_amdgcn_rcpf(1.0f + e10);
    out[b]              = o0;
    out[(size_t)Bn + b] = 1.0f - o0;
}

extern "C" void kernel_launch(void* const* d_in, const int* in_sizes, int n_in,
                              void* d_out, int out_size, void* d_ws, size_t ws_size,
                              hipStream_t stream) {
    const float* num_x = (const float*)d_in[0];
    const float* cat_x = (const float*)d_in[1];
    const float* W     = (const float*)d_in[2];
    const float* M     = (const float*)d_in[3];
    float* out = (float*)d_out;

    dim3 grid(Bn / 256), block(256);
    hipLaunchKernelGGL(model_kernel, grid, block, 0, stream,
                       num_x, cat_x, W, M, out);
}